// Round 1
// baseline (19373.309 us; speedup 1.0000x reference)
//
#include <hip/hip_runtime.h>
#include <stdint.h>

// ---------------------------------------------------------------------------
// RNN speech decoder: day-affine + softsign -> strided frames -> 5x BiGRU ->
// dense -> log_softmax.
// Strategy:
//   * All big input-gate GEMMs: bf16 MFMA 16x16x32, 128x128x64 tiles, fp32->bf16
//     conversion in LDS staging (A-gather / A-splitK variants for frame and
//     concat inputs).
//   * Sequential GRU scans: 32 WGs per direction, weights register-resident,
//     cross-WG step sync via data-as-flag polling on 0xAAAAAAAA-poisoned
//     per-(layer,dir) h buffers with agent-scope atomics.
//   * h buffers double as next layer's GEMM A operand (split-K concat).
// Workspace: ~101 MB (hbuf 40 + gi 25.2 + hpad 16.8 + whpack 15.7 + misc).
// ---------------------------------------------------------------------------

#define T_SEQ 2048
#define DH    512
#define G3    1536

typedef __attribute__((ext_vector_type(8))) short short8;   // 8 bf16
typedef __attribute__((ext_vector_type(4))) float f32x4;

__device__ inline unsigned int pack_bf16(float a, float b){
  unsigned int ua = __float_as_uint(a); ua = (ua + 0x7FFFu + ((ua>>16)&1u)) >> 16;
  unsigned int ub = __float_as_uint(b); ub = (ub + 0x7FFFu + ((ub>>16)&1u)) >> 16;
  return (ub<<16) | (ua & 0xFFFFu);
}
__device__ inline float bf2f(unsigned int h){ return __uint_as_float(h<<16); }

// ---------------------------------------------------------------------------
// General tiled GEMM: C(MxN fp32) = A(MxK fp32) @ B(KxN fp32, row-major) + bias
// amode: 0 = plain A (lda=K)
//        1 = frame-gather: A = h_pad (8223x512), row = m*4 + k/512, col = k%512
//        2 = split-K concat: k<512 -> A[m*512+k], else A2[m*512+k-512] (K=1024)
// emode: 0 = store C[m*N+n] = acc + bias[n]
//        1 = softsign( acc + bias[n] ) stored to C[(m+31)*512 + n]  (day stage)
// M%128==0, N%128==0, K%64==0 assumed (true for all uses here).
// ---------------------------------------------------------------------------
#define GBM 128
#define GBN 128
#define GBK 64
#define LSTR 36   // LDS row stride in dwords (pairs), keeps b128 16B-aligned

__global__ __launch_bounds__(256)
void gemm_kernel(const float* __restrict__ A, const float* __restrict__ A2,
                 const float* __restrict__ B, const float* __restrict__ bias,
                 float* __restrict__ C, int M, int N, int K, int amode, int emode)
{
  __shared__ __align__(16) unsigned int aL[GBM*LSTR];
  __shared__ __align__(16) unsigned int bL[GBN*LSTR];
  const int tid = threadIdx.x;
  const int m0 = blockIdx.x * GBM;
  const int n0 = blockIdx.y * GBN;
  const int lane = tid & 63;
  const int w = tid >> 6;
  const int wm = (w & 1) * 64;
  const int wn = (w >> 1) * 64;
  const int ln = lane & 15;
  const int q  = lane >> 4;

  f32x4 acc[4][4];
#pragma unroll
  for (int i=0;i<4;i++)
#pragma unroll
    for (int j=0;j<4;j++) acc[i][j] = (f32x4)0.f;

  const int ar = tid >> 1;         // A stage: row 0..127
  const int ah = tid & 1;          // A stage: 32-col half
  const int bn = (tid & 31) * 4;   // B stage: 4 cols
  const int bk = (tid >> 5) * 8;   // B stage: 8 k-rows

  const int KT = K / GBK;
  for (int kt = 0; kt < KT; kt++){
    // ---- stage A tile (128 x 64) as packed bf16 pairs, row stride LSTR dwords
    {
      const float* ap;
      if (amode == 0)      ap = A + (size_t)(m0+ar)*K + (size_t)kt*GBK + ah*32;
      else if (amode == 1) ap = A + (size_t)((m0+ar)*4 + (kt>>3))*512 + (kt&7)*64 + ah*32;
      else {
        int k0 = kt*GBK;
        const float* base = (k0 < 512) ? (A + (size_t)(m0+ar)*512 + k0)
                                       : (A2 + (size_t)(m0+ar)*512 + (k0-512));
        ap = base + ah*32;
      }
      float4 av[8];
#pragma unroll
      for (int g=0; g<8; g++) av[g] = ((const float4*)ap)[g];
#pragma unroll
      for (int g=0; g<8; g++){
        aL[ar*LSTR + ah*16 + g*2    ] = pack_bf16(av[g].x, av[g].y);
        aL[ar*LSTR + ah*16 + g*2 + 1] = pack_bf16(av[g].z, av[g].w);
      }
    }
    // ---- stage B tile (64 x 128) transposed: bL[n][k-pair]
    {
      const float* bp = B + (size_t)(kt*GBK + bk)*N + n0 + bn;
      float4 bv[8];
#pragma unroll
      for (int i=0;i<8;i++) bv[i] = *(const float4*)(bp + (size_t)i*N);
#pragma unroll
      for (int nn=0;nn<4;nn++){
#pragma unroll
        for (int kp=0;kp<4;kp++){
          float lo = ((const float*)&bv[2*kp  ])[nn];
          float hi = ((const float*)&bv[2*kp+1])[nn];
          bL[(bn+nn)*LSTR + (bk>>1) + kp] = pack_bf16(lo, hi);
        }
      }
    }
    __syncthreads();
#pragma unroll
    for (int ks=0; ks<2; ks++){
      short8 af[4], bf[4];
#pragma unroll
      for (int i=0;i<4;i++){
        uint4 u = *(const uint4*)&aL[(wm + i*16 + ln)*LSTR + ks*16 + q*4];
        af[i] = *(const short8*)&u;
      }
#pragma unroll
      for (int j=0;j<4;j++){
        uint4 u = *(const uint4*)&bL[(wn + j*16 + ln)*LSTR + ks*16 + q*4];
        bf[j] = *(const short8*)&u;
      }
#pragma unroll
      for (int i=0;i<4;i++)
#pragma unroll
        for (int j=0;j<4;j++)
          acc[i][j] = __builtin_amdgcn_mfma_f32_16x16x32_bf16(af[i], bf[j], acc[i][j], 0,0,0);
    }
    __syncthreads();
  }
  // ---- epilogue. D: col=lane&15 (n), row=quad*4+reg (m)
#pragma unroll
  for (int i=0;i<4;i++){
#pragma unroll
    for (int j=0;j<4;j++){
      int n = n0 + wn + j*16 + ln;
      float bs = bias ? bias[n] : 0.f;
#pragma unroll
      for (int r=0;r<4;r++){
        int m = m0 + wm + i*16 + q*4 + r;
        float v = acc[i][j][r] + bs;
        if (emode == 1){ v = v / (1.f + fabsf(v)); C[(size_t)(m+31)*512 + n] = v; }
        else           { C[(size_t)m*N + n] = v; }
      }
    }
  }
}

// ---------------------------------------------------------------------------
// GRU scan. Grid = 64 WGs (dir = blockIdx/32, slice j = blockIdx%32), 768 thr.
// Worker (c=tid/16 in [0,48), s=tid%16): gate-col Cg = (c/16)*512 + j*16 + c%16,
// rows (2s+32jj, 2s+32jj+1) jj=0..15 -> 32 fp32 weights in registers.
// Step: poll 512 words of hbuf[t_prev] (data-as-flag vs 0xAAAAAAAA) -> LDS,
// dot via float2, shfl-reduce over 16 segs, 16 gate lanes do sigmoid/tanh and
// publish h_t slice with agent-scope atomic stores.
// ---------------------------------------------------------------------------
__global__ __launch_bounds__(768)
void scan_kernel(const float* __restrict__ giF, const float* __restrict__ giB,
                 const unsigned int* __restrict__ wpF, const unsigned int* __restrict__ wpB,
                 const float* __restrict__ bhnF, const float* __restrict__ bhnB,
                 unsigned int* __restrict__ hbF, unsigned int* __restrict__ hbB)
{
  const int dir = blockIdx.x >> 5;
  const int j   = blockIdx.x & 31;
  const float* gi = dir ? giB : giF;
  const unsigned int* wp = dir ? wpB : wpF;
  const float* bhn = dir ? bhnB : bhnF;
  unsigned int* hb = dir ? hbB : hbF;

  const int tid = threadIdx.x;
  const int c = tid >> 4;          // 0..47
  const int s = tid & 15;
  const int Cg = (c >> 4)*512 + j*16 + (c & 15);

  float w[32];
  {
    const uint4* p = (const uint4*)(wp + ((size_t)Cg*16 + s)*16);
#pragma unroll
    for (int t4=0;t4<4;t4++){
      uint4 d = p[t4];
      unsigned int dd[4] = {d.x, d.y, d.z, d.w};
#pragma unroll
      for (int e=0;e<4;e++){
        w[t4*8 + e*2    ] = bf2f(dd[e] & 0xFFFFu);
        w[t4*8 + e*2 + 1] = bf2f(dd[e] >> 16);
      }
    }
  }

  __shared__ __align__(16) float hl[512];
  __shared__ float ghl[48];
  __shared__ float gil[48];
  float bh = 0.f;
  if (tid < 16) bh = bhn[j*16 + tid];
  if (tid < 512) hl[tid] = 0.f;
  __syncthreads();

  const unsigned int POISON = 0xAAAAAAAAu;
  for (int idx = 0; idx < T_SEQ; idx++){
    const int t = dir ? (T_SEQ-1-idx) : idx;
    // prefetch input-gate slice (issued before poll so it overlaps the spin)
    float gv = 0.f;
    if (tid < 48) gv = gi[(size_t)t*G3 + (tid>>4)*512 + j*16 + (tid&15)];
    if (idx > 0 && tid < 512){
      const unsigned int* hp = hb + (size_t)(dir ? t+1 : t-1)*DH + tid;
      unsigned int v;
      do { v = __hip_atomic_load(hp, __ATOMIC_RELAXED, __HIP_MEMORY_SCOPE_AGENT); }
      while (v == POISON);
      hl[tid] = __uint_as_float(v);
    }
    if (tid < 48) gil[tid] = gv;
    __syncthreads();

    float acc = 0.f;
#pragma unroll
    for (int jj=0;jj<16;jj++){
      float2 hh = ((const float2*)hl)[s + 16*jj];   // rows 2s+32jj, +1
      acc += w[2*jj]*hh.x + w[2*jj+1]*hh.y;
    }
#pragma unroll
    for (int off=1; off<16; off<<=1) acc += __shfl_xor(acc, off, 64);
    if (s == 0) ghl[c] = acc;
    __syncthreads();

    if (tid < 16){
      float r  = 1.f/(1.f + __expf(-(gil[tid]    + ghl[tid])));
      float z  = 1.f/(1.f + __expf(-(gil[16+tid] + ghl[16+tid])));
      float nn = tanhf(gil[32+tid] + r*(ghl[32+tid] + bh));
      float hprev = hl[j*16 + tid];
      float hnew = (1.f - z)*nn + z*hprev;
      unsigned int bits = __float_as_uint(hnew);
      if (bits == POISON) bits ^= 1u;   // never publish the sentinel
      __hip_atomic_store(hb + (size_t)t*DH + j*16 + tid, bits,
                         __ATOMIC_RELAXED, __HIP_MEMORY_SCOPE_AGENT);
    }
    __syncthreads();   // protect gil/ghl/hl against next-step overwrites
  }
}

// ---------------------------------------------------------------------------
// Decoder: logits = [hf|hb] @ Wdec + bdec, then row log_softmax. One wave/row.
// ---------------------------------------------------------------------------
__global__ __launch_bounds__(64)
void decoder_kernel(const unsigned int* __restrict__ hf, const unsigned int* __restrict__ hbk,
                    const float* __restrict__ Wd, const float* __restrict__ bd,
                    float* __restrict__ out)
{
  const int t = blockIdx.x;
  const int lane = threadIdx.x;
  __shared__ float y[1024];
  for (int i = lane; i < 512; i += 64){
    y[i]       = __uint_as_float(hf [(size_t)t*512 + i]);
    y[512 + i] = __uint_as_float(hbk[(size_t)t*512 + i]);
  }
  __syncthreads();
  float v = -1e30f;
  if (lane < 41){
    float acc = bd[lane];
    for (int k=0;k<1024;k++) acc += y[k] * Wd[(size_t)k*41 + lane];
    v = acc;
  }
  float m = v;
#pragma unroll
  for (int off=32; off; off>>=1) m = fmaxf(m, __shfl_xor(m, off, 64));
  float e = (lane < 41) ? __expf(v - m) : 0.f;
  float ssum = e;
#pragma unroll
  for (int off=32; off; off>>=1) ssum += __shfl_xor(ssum, off, 64);
  if (lane < 41) out[(size_t)t*41 + lane] = (v - m) - __logf(ssum);
}

// ---------------------------------------------------------------------------
// Prep kernels
// ---------------------------------------------------------------------------
__global__ void poison_kernel(unsigned int* p, long n){
  long i = (long)blockIdx.x*blockDim.x + threadIdx.x;
  long st = (long)gridDim.x*blockDim.x;
  for (; i < n; i += st) p[i] = 0xAAAAAAAAu;
}
__global__ void zero_kernel(float* p, int n){
  int i = blockIdx.x*blockDim.x + threadIdx.x;
  if (i < n) p[i] = 0.f;
}
__global__ void daysel_kernel(const float* __restrict__ dw, const float* __restrict__ db,
                              const int* __restrict__ didx, float* __restrict__ wt,
                              float* __restrict__ bsel){
  int d = *didx;
  int i = blockIdx.x*256 + threadIdx.x;
  if (i < 512*512){
    int k = i >> 9, n = i & 511;
    wt[i] = dw[(size_t)d*262144 + (size_t)n*512 + k];   // wt[k][n] = W[n][k]
  }
  if (i < 512) bsel[i] = db[(size_t)d*512 + i];
}
struct WhPtrs { const float* p[10]; };
__global__ void whpack_kernel(WhPtrs wps, unsigned int* __restrict__ dst){
  long i = (long)blockIdx.x*256 + threadIdx.x;
  if (i >= 10L*393216L) return;
  int ld  = (int)(i / 393216);
  int rem = (int)(i % 393216);
  int jj = rem & 15, s = (rem>>4)&15, C = rem >> 8;
  const float* W = wps.p[ld];
  dst[i] = pack_bf16(W[(size_t)(2*s+32*jj  )*G3 + C],
                     W[(size_t)(2*s+32*jj+1)*G3 + C]);
}

// ---------------------------------------------------------------------------
extern "C" void kernel_launch(void* const* d_in, const int* in_sizes, int n_in,
                              void* d_out, int out_size, void* d_ws, size_t ws_size,
                              hipStream_t stream)
{
  const float* x     = (const float*)d_in[0];
  const int*   didx  = (const int*)  d_in[1];
  const float* dayW  = (const float*)d_in[2];
  const float* dayB  = (const float*)d_in[3];
  const float* Wi0f  = (const float*)d_in[4];
  const float* bi0f  = (const float*)d_in[5];
  const float* Wh0f  = (const float*)d_in[6];
  const float* bhn0f = (const float*)d_in[7];
  const float* Wi0b  = (const float*)d_in[8];
  const float* bi0b  = (const float*)d_in[9];
  const float* Wh0b  = (const float*)d_in[10];
  const float* bhn0b = (const float*)d_in[11];
  const float* WiRf  = (const float*)d_in[12];
  const float* biRf  = (const float*)d_in[13];
  const float* WhRf  = (const float*)d_in[14];
  const float* bhnRf = (const float*)d_in[15];
  const float* WiRb  = (const float*)d_in[16];
  const float* biRb  = (const float*)d_in[17];
  const float* WhRb  = (const float*)d_in[18];
  const float* bhnRb = (const float*)d_in[19];
  const float* Wdec  = (const float*)d_in[20];
  const float* bdec  = (const float*)d_in[21];
  float* out = (float*)d_out;

  char* ws = (char*)d_ws;
  size_t off = 0;
  unsigned int* hbuf[5][2];
  for (int l=0;l<5;l++) for (int d=0;d<2;d++){ hbuf[l][d] = (unsigned int*)(ws+off); off += (size_t)2048*512*4; }
  float* giF  = (float*)(ws+off); off += (size_t)2048*1536*4;
  float* giB  = (float*)(ws+off); off += (size_t)2048*1536*4;
  float* hpad = (float*)(ws+off); off += (size_t)8223*512*4;
  float* dayWT= (float*)(ws+off); off += (size_t)512*512*4;
  float* bsel = (float*)(ws+off); off += 2048;
  unsigned int* whp = (unsigned int*)(ws+off); off += (size_t)10*393216*4;
  // total ~101 MB; ws_size assumed >= this.

  // --- prep
  hipLaunchKernelGGL(poison_kernel, dim3(1024), dim3(256), 0, stream,
                     hbuf[0][0], (long)5*2*2048*512);
  hipLaunchKernelGGL(zero_kernel, dim3((31*512+255)/256), dim3(256), 0, stream,
                     hpad, 31*512);
  hipLaunchKernelGGL(daysel_kernel, dim3(1024), dim3(256), 0, stream,
                     dayW, dayB, didx, dayWT, bsel);
  WhPtrs wps;
  wps.p[0] = Wh0f; wps.p[1] = Wh0b;
  for (int l=0;l<4;l++){
    wps.p[2+2*l] = WhRf + (size_t)l*512*1536;
    wps.p[3+2*l] = WhRb + (size_t)l*512*1536;
  }
  hipLaunchKernelGGL(whpack_kernel, dim3((10*393216+255)/256), dim3(256), 0, stream,
                     wps, whp);

  // --- day transform + softsign -> hpad rows 31..8222 (rows 0..30 zeroed)
  hipLaunchKernelGGL(gemm_kernel, dim3(64,4), dim3(256), 0, stream,
                     x, (const float*)nullptr, dayWT, bsel, hpad,
                     8192, 512, 512, 0, 1);

  // --- layer 0 input gates (frame gather), then scan
  hipLaunchKernelGGL(gemm_kernel, dim3(16,12), dim3(256), 0, stream,
                     hpad, (const float*)nullptr, Wi0f, bi0f, giF,
                     2048, 1536, 16384, 1, 0);
  hipLaunchKernelGGL(gemm_kernel, dim3(16,12), dim3(256), 0, stream,
                     hpad, (const float*)nullptr, Wi0b, bi0b, giB,
                     2048, 1536, 16384, 1, 0);
  hipLaunchKernelGGL(scan_kernel, dim3(64), dim3(768), 0, stream,
                     giF, giB, whp, whp + 393216, bhn0f, bhn0b,
                     hbuf[0][0], hbuf[0][1]);

  // --- layers 1..4
  for (int l=1;l<5;l++){
    const float* Af = (const float*)hbuf[l-1][0];
    const float* Ab = (const float*)hbuf[l-1][1];
    hipLaunchKernelGGL(gemm_kernel, dim3(16,12), dim3(256), 0, stream,
                       Af, Ab, WiRf + (size_t)(l-1)*1024*1536, biRf + (l-1)*1536, giF,
                       2048, 1536, 1024, 2, 0);
    hipLaunchKernelGGL(gemm_kernel, dim3(16,12), dim3(256), 0, stream,
                       Af, Ab, WiRb + (size_t)(l-1)*1024*1536, biRb + (l-1)*1536, giB,
                       2048, 1536, 1024, 2, 0);
    hipLaunchKernelGGL(scan_kernel, dim3(64), dim3(768), 0, stream,
                       giF, giB, whp + (size_t)(2*l)*393216, whp + (size_t)(2*l+1)*393216,
                       bhnRf + (l-1)*512, bhnRb + (l-1)*512,
                       hbuf[l][0], hbuf[l][1]);
  }

  // --- decoder + log_softmax
  hipLaunchKernelGGL(decoder_kernel, dim3(2048), dim3(64), 0, stream,
                     hbuf[4][0], hbuf[4][1], Wdec, bdec, out);
}